// Round 1
// baseline (1117.054 us; speedup 1.0000x reference)
//
#include <hip/hip_runtime.h>
#include <math.h>

// Problem constants (B=4096, V=32000 per setup_inputs; B derived from in_sizes).
constexpr int V_DIM  = 32000;
constexpr int NV4    = V_DIM / 4;          // 8000 float4 per row
constexpr int TPB    = 1024;               // 16 waves
constexpr int NCHUNK = (NV4 + TPB - 1) / TPB;  // 8 float4 per thread
constexpr int CAP    = 8192;               // active-set capacity (32 KB LDS)
constexpr int N_ITER = 50;

__global__ void zero_out_kernel(float* out) { out[0] = 0.0f; }

__global__ __launch_bounds__(TPB, 4) void entmax_loss_kernel(
    const float* __restrict__ X, const float* __restrict__ T,
    float* __restrict__ out, int B)
{
  const int row  = blockIdx.x;
  const float*  Xr = X + (size_t)row * V_DIM;
  const float4* X4 = (const float4*)Xr;
  const float4* T4 = (const float4*)(T + (size_t)row * V_DIM);
  const int tid  = threadIdx.x;
  const int lane = tid & 63;
  const int wid  = tid >> 6;

  __shared__ float s_wmax[16];
  __shared__ float s_wsum[16];
  __shared__ float s_res[2];      // [0]=row max(x), [1]=sum(t*x)
  __shared__ int   s_cnt;
  __shared__ float s_act[CAP];    // active xs = 0.5*x values

  // ---- Pass 1: stream row; keep x in registers, reduce max and t·x ----
  float4 xv[NCHUNK];
  float tmax = -INFINITY;
  float ttx  = 0.0f;
#pragma unroll
  for (int j = 0; j < NCHUNK; ++j) {
    const int idx = tid + j * TPB;
    if (idx < NV4) {
      const float4 x = X4[idx];
      const float4 t = T4[idx];
      xv[j] = x;
      tmax = fmaxf(tmax, fmaxf(fmaxf(x.x, x.y), fmaxf(x.z, x.w)));
      ttx += x.x * t.x;
      ttx += x.y * t.y;
      ttx += x.z * t.z;
      ttx += x.w * t.w;
    } else {
      xv[j] = make_float4(-INFINITY, -INFINITY, -INFINITY, -INFINITY);
    }
  }

  // wave-level butterfly reduce (64 lanes)
#pragma unroll
  for (int o = 32; o >= 1; o >>= 1) {
    tmax = fmaxf(tmax, __shfl_xor(tmax, o));
    ttx += __shfl_xor(ttx, o);
  }
  if (lane == 0) { s_wmax[wid] = tmax; s_wsum[wid] = ttx; }
  if (tid == 0)  { s_cnt = 0; }
  __syncthreads();
  if (wid == 0) {
    float m = (lane < 16) ? s_wmax[lane] : -INFINITY;
    float s = (lane < 16) ? s_wsum[lane] : 0.0f;
#pragma unroll
    for (int o = 8; o >= 1; o >>= 1) {
      m = fmaxf(m, __shfl_xor(m, o));
      s += __shfl_xor(s, o);
    }
    if (lane == 0) { s_res[0] = m; s_res[1] = s; }
  }
  __syncthreads();

  const float maxX   = s_res[0];
  const float sum_tx = s_res[1];
  const float thr    = maxX - 2.0f;  // active iff x > max(x) - 2  (xs > maxXs - 1)

  // ---- Compact active set into LDS (store xs = 0.5*x) ----
#pragma unroll
  for (int j = 0; j < NCHUNK; ++j) {
    const int idx = tid + j * TPB;
    if (idx < NV4) {
      const float4 x = xv[j];
      if (x.x > thr) { int i = atomicAdd(&s_cnt, 1); if (i < CAP) s_act[i] = 0.5f * x.x; }
      if (x.y > thr) { int i = atomicAdd(&s_cnt, 1); if (i < CAP) s_act[i] = 0.5f * x.y; }
      if (x.z > thr) { int i = atomicAdd(&s_cnt, 1); if (i < CAP) s_act[i] = 0.5f * x.z; }
      if (x.w > thr) { int i = atomicAdd(&s_cnt, 1); if (i < CAP) s_act[i] = 0.5f * x.w; }
    }
  }
  __syncthreads();

  // ---- Wave 0: bisection + epilogue over the active set ----
  if (wid == 0) {
    const int  n_act   = s_cnt;
    const bool use_lds = (n_act <= CAP);    // fallback: rescan global (never expected)
    const int  n       = use_lds ? n_act : V_DIM;

    const float maxXs  = 0.5f * maxX;
    const float tau_hi = maxXs - sqrtf(1.0f / (float)V_DIM);  // (1/d)^(alpha-1)
    float tau_lo = maxXs - 1.0f;

    // f_lo = sum relu(xs - tau_lo)^2 - 1  (inactive elements contribute exact 0)
    float s = 0.0f;
    for (int i = lane; i < n; i += 64) {
      const float xs = use_lds ? s_act[i] : 0.5f * Xr[i];
      const float r  = fmaxf(xs - tau_lo, 0.0f);
      s = fmaf(r, r, s);
    }
#pragma unroll
    for (int o = 32; o >= 1; o >>= 1) s += __shfl_xor(s, o);
    const float f_lo = s - 1.0f;

    float dm    = tau_hi - tau_lo;
    float tau_m = tau_lo;
    for (int it = 0; it < N_ITER; ++it) {
      dm *= 0.5f;
      tau_m = tau_lo + dm;
      float sm = 0.0f;
      for (int i = lane; i < n; i += 64) {
        const float xs = use_lds ? s_act[i] : 0.5f * Xr[i];
        const float r  = fmaxf(xs - tau_m, 0.0f);
        sm = fmaf(r, r, sm);
      }
#pragma unroll
      for (int o = 32; o >= 1; o >>= 1) sm += __shfl_xor(sm, o);
      const float f_m = sm - 1.0f;
      if (f_m * f_lo >= 0.0f) tau_lo = tau_m;   // uniform across wave
    }

    // Epilogue: S = sum q, Q3 = sum q^1.5 = sum r^3, PX = sum q*x (x = 2*xs)
    float S = 0.0f, Q3 = 0.0f, PX = 0.0f;
    for (int i = lane; i < n; i += 64) {
      const float xs = use_lds ? s_act[i] : 0.5f * Xr[i];
      const float r  = fmaxf(xs - tau_m, 0.0f);
      const float r2 = r * r;
      S  += r2;
      Q3 += r2 * r;
      PX += r2 * (2.0f * xs);
    }
#pragma unroll
    for (int o = 32; o >= 1; o >>= 1) {
      S  += __shfl_xor(S, o);
      Q3 += __shfl_xor(Q3, o);
      PX += __shfl_xor(PX, o);
    }
    if (lane == 0) {
      // omega = (1 - sum(p^1.5)) / (alpha*(alpha-1)),  sum(p^1.5) = Q3 / S^1.5
      const float omega = (1.0f - Q3 / (S * sqrtf(S))) * (1.0f / 0.75f);
      const float loss  = omega + PX / S - sum_tx;
      atomicAdd(out, loss * (1.0f / (float)B));
    }
  }
}

extern "C" void kernel_launch(void* const* d_in, const int* in_sizes, int n_in,
                              void* d_out, int out_size, void* d_ws, size_t ws_size,
                              hipStream_t stream) {
  const float* logits  = (const float*)d_in[0];
  const float* targets = (const float*)d_in[1];
  float* out = (float*)d_out;
  const int B = in_sizes[0] / V_DIM;

  zero_out_kernel<<<1, 1, 0, stream>>>(out);
  entmax_loss_kernel<<<B, TPB, 0, stream>>>(logits, targets, out, B);
}